// Round 1
// baseline (3157.542 us; speedup 1.0000x reference)
//
#include <hip/hip_runtime.h>
#include <math.h>

#define NEG_SLOPE 0.2f

// Monotone float<->uint encoding so atomicMax works on floats (incl. negatives).
__device__ __forceinline__ unsigned enc_f32(float x) {
    unsigned u = __float_as_uint(x);
    return (u & 0x80000000u) ? ~u : (u | 0x80000000u);
}
__device__ __forceinline__ float dec_f32(unsigned u) {
    return __uint_as_float((u & 0x80000000u) ? (u ^ 0x80000000u) : ~u);
}

// ---- GEMM1: h1[n][t] = dot(x[n][0:256], W1[t][0:256]); fused score dots ----
__global__ void gemm1_kernel(const float* __restrict__ x, const float* __restrict__ W1,
                             const float* __restrict__ asrc, const float* __restrict__ adst,
                             float* __restrict__ h1, float* __restrict__ s1,
                             float* __restrict__ d1) {
    const int n = blockIdx.x;
    const int t = threadIdx.x;  // 0..127
    __shared__ float xs[256];
    __shared__ float rs[2], rd[2];
    const float* xr = x + (size_t)n * 256;
    xs[t] = xr[t];
    xs[t + 128] = xr[t + 128];
    __syncthreads();
    const float* w = W1 + t * 256;
    float acc = 0.f;
#pragma unroll 8
    for (int k = 0; k < 256; ++k) acc = fmaf(xs[k], w[k], acc);
    h1[(size_t)n * 128 + t] = acc;
    // fused scores: s1[n] = sum_t h1[n][t]*asrc[t], same for d1
    float vs = acc * asrc[t];
    float vd = acc * adst[t];
#pragma unroll
    for (int off = 32; off >= 1; off >>= 1) {
        vs += __shfl_down(vs, off);
        vd += __shfl_down(vd, off);
    }
    const int wave = t >> 6, lane = t & 63;
    if (lane == 0) { rs[wave] = vs; rd[wave] = vd; }
    __syncthreads();
    if (t == 0) { s1[n] = rs[0] + rs[1]; d1[n] = rd[0] + rd[1]; }
}

// ---- GEMM2: reads ELU(g1) on the fly; h2[n][t] = dot(elu(g1[n]), W2[t]) ----
__global__ void gemm2_kernel(const float* __restrict__ g1, const float* __restrict__ W2,
                             const float* __restrict__ asrc, const float* __restrict__ adst,
                             float* __restrict__ h2, float* __restrict__ s2,
                             float* __restrict__ d2) {
    const int n = blockIdx.x;
    const int t = threadIdx.x;  // 0..63 (one wave)
    __shared__ float xs[128];
    const float* gr = g1 + (size_t)n * 128;
    float v0 = gr[t], v1 = gr[t + 64];
    xs[t] = v0 > 0.f ? v0 : expm1f(v0);
    xs[t + 64] = v1 > 0.f ? v1 : expm1f(v1);
    __syncthreads();
    const float* w = W2 + t * 128;
    float acc = 0.f;
#pragma unroll 8
    for (int k = 0; k < 128; ++k) acc = fmaf(xs[k], w[k], acc);
    h2[(size_t)n * 64 + t] = acc;
    float vs = acc * asrc[t];
    float vd = acc * adst[t];
#pragma unroll
    for (int off = 32; off >= 1; off >>= 1) {
        vs += __shfl_down(vs, off);
        vd += __shfl_down(vd, off);
    }
    if (t == 0) { s2[n] = vs; d2[n] = vd; }
}

// ---- Edge pass A: e = leakyrelu(s[row]+d[col]); atomic segment max on row ----
__global__ void edge_max_kernel(const int* __restrict__ row, const int* __restrict__ col,
                                const float* __restrict__ s, const float* __restrict__ d,
                                float* __restrict__ e_out, unsigned* __restrict__ m_enc,
                                int E) {
    int i = blockIdx.x * blockDim.x + threadIdx.x;
    if (i >= E) return;
    int r = row[i], c = col[i];
    float e = s[r] + d[c];
    e = (e >= 0.f) ? e : NEG_SLOPE * e;
    e_out[i] = e;
    atomicMax(&m_enc[r], enc_f32(e));
}

// ---- Edge pass B: ex = exp(e - m[row]); atomic segment sum of denominators ----
__global__ void edge_exp_kernel(const int* __restrict__ row, const float* __restrict__ e_in,
                                const unsigned* __restrict__ m_enc, float* __restrict__ ex_out,
                                float* __restrict__ denom, int E) {
    int i = blockIdx.x * blockDim.x + threadIdx.x;
    if (i >= E) return;
    int r = row[i];
    float ex = __expf(e_in[i] - dec_f32(m_enc[r]));
    ex_out[i] = ex;
    atomicAdd(&denom[r], ex);
}

// ---- SpMM scatter: out[row] += (ex/denom[row]) * feats[col], D floats/edge ----
template <int D>
__global__ void spmm_kernel(const int* __restrict__ row, const int* __restrict__ col,
                            const float* __restrict__ ex, const float* __restrict__ denom,
                            const float* __restrict__ feats, float* __restrict__ out, int E) {
    const int EPB = 256 / D;
    int e = blockIdx.x * EPB + (threadIdx.x / D);
    int dd = threadIdx.x % D;
    if (e >= E) return;
    int r = row[e], c = col[e];
    float a = ex[e] / denom[r];
    atomicAdd(&out[(size_t)r * D + dd], a * feats[(size_t)c * D + dd]);
}

extern "C" void kernel_launch(void* const* d_in, const int* in_sizes, int n_in,
                              void* d_out, int out_size, void* d_ws, size_t ws_size,
                              hipStream_t stream) {
    const float* x   = (const float*)d_in[0];
    const int*   edg = (const int*)d_in[1];
    const float* W1  = (const float*)d_in[2];
    const float* W2  = (const float*)d_in[3];
    const float* as1 = (const float*)d_in[4];
    const float* ad1 = (const float*)d_in[5];
    const float* as2 = (const float*)d_in[6];
    const float* ad2 = (const float*)d_in[7];

    const int N = in_sizes[0] / 256;
    const int E = in_sizes[1] / 2;
    const int* row = edg;
    const int* col = edg + E;

    // Workspace layout (all f32 unless noted)
    char* p = (char*)d_ws;
    float* h1 = (float*)p;  p += (size_t)N * 128 * 4;   // layer1 features (reused as h2)
    float* g1 = (float*)p;  p += (size_t)N * 128 * 4;   // GAT1 output (pre-ELU)
    float* ex = (float*)p;  p += (size_t)E * 4;         // per-edge e / exp
    float* sm = (float*)p;  p += (size_t)N * 8 * 4;     // 8 per-node arrays, zeroed as one
    float*    s1   = sm + (size_t)N * 0;
    float*    d1   = sm + (size_t)N * 1;
    unsigned* m1   = (unsigned*)(sm + (size_t)N * 2);
    float*    den1 = sm + (size_t)N * 3;
    float*    s2   = sm + (size_t)N * 4;
    float*    d2   = sm + (size_t)N * 5;
    unsigned* m2   = (unsigned*)(sm + (size_t)N * 6);
    float*    den2 = sm + (size_t)N * 7;
    float* h2 = h1;  // h1 dead after SpMM1

    // Zero accumulators (capture-safe stream memsets)
    hipMemsetAsync(g1, 0, (size_t)N * 128 * 4, stream);
    hipMemsetAsync(sm, 0, (size_t)N * 8 * 4, stream);
    hipMemsetAsync(d_out, 0, (size_t)out_size * 4, stream);

    const int EB = (E + 255) / 256;

    // Layer 1
    gemm1_kernel<<<N, 128, 0, stream>>>(x, W1, as1, ad1, h1, s1, d1);
    edge_max_kernel<<<EB, 256, 0, stream>>>(row, col, s1, d1, ex, m1, E);
    edge_exp_kernel<<<EB, 256, 0, stream>>>(row, ex, m1, ex, den1, E);
    spmm_kernel<128><<<(E + 1) / 2, 256, 0, stream>>>(row, col, ex, den1, h1, g1, E);

    // Layer 2 (ELU fused into GEMM2 load)
    gemm2_kernel<<<N, 64, 0, stream>>>(g1, W2, as2, ad2, h2, s2, d2);
    edge_max_kernel<<<EB, 256, 0, stream>>>(row, col, s2, d2, ex, m2, E);
    edge_exp_kernel<<<EB, 256, 0, stream>>>(row, ex, m2, ex, den2, E);
    spmm_kernel<64><<<(E + 3) / 4, 256, 0, stream>>>(row, col, ex, den2, h2, (float*)d_out, E);
}

// Round 2
// 1501.063 us; speedup vs baseline: 2.1035x; 2.1035x over previous
//
#include <hip/hip_runtime.h>
#include <math.h>

#define NEG_SLOPE 0.2f

// Monotone float<->uint encoding so atomicMax works on floats (incl. negatives).
__device__ __forceinline__ unsigned enc_f32(float x) {
    unsigned u = __float_as_uint(x);
    return (u & 0x80000000u) ? ~u : (u | 0x80000000u);
}
__device__ __forceinline__ float dec_f32(unsigned u) {
    return __uint_as_float((u & 0x80000000u) ? (u ^ 0x80000000u) : ~u);
}

// ---- tiny one-time transpose: src [R][C] -> dst [C][R] ----
__global__ void transpose_kernel(const float* __restrict__ src, float* __restrict__ dst,
                                 int R, int C) {
    int idx = blockIdx.x * blockDim.x + threadIdx.x;
    if (idx >= R * C) return;
    int k = idx % C, n = idx / C;
    dst[(size_t)k * R + n] = src[(size_t)n * C + k];
}

// ---- Register-blocked tiled GEMM: H[n][o] = dot(act(A[n][:]), WT[:][o]) ----
// WT is pre-transposed weights [K][OUT]. Fused per-node score dots s,d.
template <int K, int OUT, int TN, bool ELU>
__global__ __launch_bounds__(256) void gemm_fused(
        const float* __restrict__ A, const float* __restrict__ WT,
        const float* __restrict__ asrc, const float* __restrict__ adst,
        float* __restrict__ H, float* __restrict__ s_out, float* __restrict__ d_out_,
        int N) {
    constexpr int BM = 128, BK = 32, TM = 8;
    constexpr int BMP = BM + 4;  // pad keeps 16B alignment, spreads scatter-write banks
    const int t = threadIdx.x;
    const int tr = t >> 4, tc = t & 15;
    const int n0 = blockIdx.x * BM;
    const int nrow = min(BM, N - n0);

    __shared__ float As[BK][BMP];   // A tile, transposed [k][m]
    __shared__ float Bs[BK][OUT];   // W tile, [k][o]

    float acc[TM][TN];
#pragma unroll
    for (int i = 0; i < TM; ++i)
#pragma unroll
        for (int j = 0; j < TN; ++j) acc[i][j] = 0.f;

    for (int k0 = 0; k0 < K; k0 += BK) {
        // stage A (BM x BK): 1024 float4s, 4 per thread, transposed scatter into As
#pragma unroll
        for (int it = 0; it < (BM * BK / 4) / 256; ++it) {
            int q = t + 256 * it;
            int m = q >> 3;      // 8 float4 per row (BK/4)
            int kq = q & 7;
            float4 v = make_float4(0.f, 0.f, 0.f, 0.f);
            if (m < nrow) v = *(const float4*)&A[(size_t)(n0 + m) * K + k0 + 4 * kq];
            if (ELU) {
                v.x = v.x > 0.f ? v.x : expm1f(v.x);
                v.y = v.y > 0.f ? v.y : expm1f(v.y);
                v.z = v.z > 0.f ? v.z : expm1f(v.z);
                v.w = v.w > 0.f ? v.w : expm1f(v.w);
            }
            As[4 * kq + 0][m] = v.x;
            As[4 * kq + 1][m] = v.y;
            As[4 * kq + 2][m] = v.z;
            As[4 * kq + 3][m] = v.w;
        }
        // stage B (BK x OUT): contiguous rows of WT, vector writes
#pragma unroll
        for (int it = 0; it < (BK * OUT / 4) / 256; ++it) {
            int q = t + 256 * it;
            int kk = q / (OUT / 4);
            int j = q % (OUT / 4);
            *(float4*)&Bs[kk][4 * j] = *(const float4*)&WT[(size_t)(k0 + kk) * OUT + 4 * j];
        }
        __syncthreads();

        for (int k = 0; k < BK; ++k) {
            float a[TM], b[TN];
            *(float4*)&a[0] = *(const float4*)&As[k][TM * tr];
            *(float4*)&a[4] = *(const float4*)&As[k][TM * tr + 4];
#pragma unroll
            for (int j4 = 0; j4 < TN / 4; ++j4)
                *(float4*)&b[4 * j4] = *(const float4*)&Bs[k][TN * tc + 4 * j4];
#pragma unroll
            for (int i = 0; i < TM; ++i)
#pragma unroll
                for (int j = 0; j < TN; ++j) acc[i][j] = fmaf(a[i], b[j], acc[i][j]);
        }
        __syncthreads();
    }

    // epilogue: store H rows + fused score dots (reduce over the 16 tc lanes)
#pragma unroll
    for (int i = 0; i < TM; ++i) {
        int m = TM * tr + i;
        if (m < nrow) {
#pragma unroll
            for (int j4 = 0; j4 < TN / 4; ++j4)
                *(float4*)&H[(size_t)(n0 + m) * OUT + TN * tc + 4 * j4] =
                    *(const float4*)&acc[i][4 * j4];
        }
    }
#pragma unroll
    for (int i = 0; i < TM; ++i) {
        float vs = 0.f, vd = 0.f;
#pragma unroll
        for (int j = 0; j < TN; ++j) {
            vs = fmaf(acc[i][j], asrc[TN * tc + j], vs);
            vd = fmaf(acc[i][j], adst[TN * tc + j], vd);
        }
#pragma unroll
        for (int off = 8; off >= 1; off >>= 1) {
            vs += __shfl_down(vs, off, 16);
            vd += __shfl_down(vd, off, 16);
        }
        int m = TM * tr + i;
        if (tc == 0 && m < nrow) {
            s_out[n0 + m] = vs;
            d_out_[n0 + m] = vd;
        }
    }
}

// ---- Edge pass A: e = leakyrelu(s[row]+d[col]); atomic segment max on row ----
__global__ void edge_max_kernel(const int* __restrict__ row, const int* __restrict__ col,
                                const float* __restrict__ s, const float* __restrict__ d,
                                float* __restrict__ e_out, unsigned* __restrict__ m_enc,
                                int E) {
    int i = blockIdx.x * blockDim.x + threadIdx.x;
    if (i >= E) return;
    int r = row[i], c = col[i];
    float e = s[r] + d[c];
    e = (e >= 0.f) ? e : NEG_SLOPE * e;
    e_out[i] = e;
    atomicMax(&m_enc[r], enc_f32(e));
}

// ---- Edge pass B: ex = exp(e - m[row]); atomic segment sum of denominators ----
__global__ void edge_exp_kernel(const int* __restrict__ row, const float* __restrict__ e_in,
                                const unsigned* __restrict__ m_enc, float* __restrict__ ex_out,
                                float* __restrict__ denom, int E) {
    int i = blockIdx.x * blockDim.x + threadIdx.x;
    if (i >= E) return;
    int r = row[i];
    float ex = __expf(e_in[i] - dec_f32(m_enc[r]));
    ex_out[i] = ex;
    atomicAdd(&denom[r], ex);
}

// ---- SpMM scatter: out[row] += (ex/denom[row]) * feats[col], D floats/edge ----
template <int D>
__global__ void spmm_kernel(const int* __restrict__ row, const int* __restrict__ col,
                            const float* __restrict__ ex, const float* __restrict__ denom,
                            const float* __restrict__ feats, float* __restrict__ out, int E) {
    const int EPB = 256 / D;
    int e = blockIdx.x * EPB + (threadIdx.x / D);
    int dd = threadIdx.x % D;
    if (e >= E) return;
    int r = row[e], c = col[e];
    float a = ex[e] / denom[r];
    atomicAdd(&out[(size_t)r * D + dd], a * feats[(size_t)c * D + dd]);
}

extern "C" void kernel_launch(void* const* d_in, const int* in_sizes, int n_in,
                              void* d_out, int out_size, void* d_ws, size_t ws_size,
                              hipStream_t stream) {
    const float* x   = (const float*)d_in[0];
    const int*   edg = (const int*)d_in[1];
    const float* W1  = (const float*)d_in[2];
    const float* W2  = (const float*)d_in[3];
    const float* as1 = (const float*)d_in[4];
    const float* ad1 = (const float*)d_in[5];
    const float* as2 = (const float*)d_in[6];
    const float* ad2 = (const float*)d_in[7];

    const int N = in_sizes[0] / 256;
    const int E = in_sizes[1] / 2;
    const int* row = edg;
    const int* col = edg + E;

    // Workspace layout
    char* p = (char*)d_ws;
    float* h1 = (float*)p;  p += (size_t)N * 128 * 4;   // layer1 features (reused as h2)
    float* g1 = (float*)p;  p += (size_t)N * 128 * 4;   // GAT1 output (pre-ELU)
    float* ex = (float*)p;  p += (size_t)E * 4;         // per-edge e / exp
    float* sm = (float*)p;  p += (size_t)N * 8 * 4;     // 8 per-node arrays, zeroed as one
    float*    s1   = sm + (size_t)N * 0;
    float*    d1   = sm + (size_t)N * 1;
    unsigned* m1   = (unsigned*)(sm + (size_t)N * 2);
    float*    den1 = sm + (size_t)N * 3;
    float*    s2   = sm + (size_t)N * 4;
    float*    d2   = sm + (size_t)N * 5;
    unsigned* m2   = (unsigned*)(sm + (size_t)N * 6);
    float*    den2 = sm + (size_t)N * 7;
    float* W1T = (float*)p; p += (size_t)256 * 128 * 4; // W1 transposed [256][128]
    float* W2T = (float*)p; p += (size_t)128 * 64 * 4;  // W2 transposed [128][64]
    float* h2 = h1;  // h1 dead after SpMM1

    // Zero accumulators (capture-safe stream memsets)
    hipMemsetAsync(g1, 0, (size_t)N * 128 * 4, stream);
    hipMemsetAsync(sm, 0, (size_t)N * 8 * 4, stream);
    hipMemsetAsync(d_out, 0, (size_t)out_size * 4, stream);

    // One-time weight transposes (tiny)
    transpose_kernel<<<(128 * 256 + 255) / 256, 256, 0, stream>>>(W1, W1T, 128, 256);
    transpose_kernel<<<(64 * 128 + 255) / 256, 256, 0, stream>>>(W2, W2T, 64, 128);

    const int EB = (E + 255) / 256;
    const int GB = (N + 127) / 128;

    // Layer 1
    gemm_fused<256, 128, 8, false><<<GB, 256, 0, stream>>>(x, W1T, as1, ad1, h1, s1, d1, N);
    edge_max_kernel<<<EB, 256, 0, stream>>>(row, col, s1, d1, ex, m1, E);
    edge_exp_kernel<<<EB, 256, 0, stream>>>(row, ex, m1, ex, den1, E);
    spmm_kernel<128><<<(E + 1) / 2, 256, 0, stream>>>(row, col, ex, den1, h1, g1, E);

    // Layer 2 (ELU fused into GEMM2 A-staging)
    gemm_fused<128, 64, 4, true><<<GB, 256, 0, stream>>>(g1, W2T, as2, ad2, h2, s2, d2, N);
    edge_max_kernel<<<EB, 256, 0, stream>>>(row, col, s2, d2, ex, m2, E);
    edge_exp_kernel<<<EB, 256, 0, stream>>>(row, ex, m2, ex, den2, E);
    spmm_kernel<64><<<(E + 3) / 4, 256, 0, stream>>>(row, col, ex, den2, h2, (float*)d_out, E);
}

// Round 3
// 655.858 us; speedup vs baseline: 4.8144x; 2.2887x over previous
//
#include <hip/hip_runtime.h>
#include <math.h>

#define NEG_SLOPE 0.2f

// ---- tiny one-time transpose: src [R][C] -> dst [C][R] ----
__global__ void transpose_kernel(const float* __restrict__ src, float* __restrict__ dst,
                                 int R, int C) {
    int idx = blockIdx.x * blockDim.x + threadIdx.x;
    if (idx >= R * C) return;
    int k = idx % C, n = idx / C;
    dst[(size_t)k * R + n] = src[(size_t)n * C + k];
}

// ---- Register-blocked tiled GEMM: H[n][o] = dot(act(A[n][:]), WT[:][o]) ----
template <int K, int OUT, int TN, bool ELU>
__global__ __launch_bounds__(256) void gemm_fused(
        const float* __restrict__ A, const float* __restrict__ WT,
        const float* __restrict__ asrc, const float* __restrict__ adst,
        float* __restrict__ H, float* __restrict__ s_out, float* __restrict__ d_out_,
        int N) {
    constexpr int BM = 128, BK = 32, TM = 8;
    constexpr int BMP = BM + 4;
    const int t = threadIdx.x;
    const int tr = t >> 4, tc = t & 15;
    const int n0 = blockIdx.x * BM;
    const int nrow = min(BM, N - n0);

    __shared__ float As[BK][BMP];
    __shared__ float Bs[BK][OUT];

    float acc[TM][TN];
#pragma unroll
    for (int i = 0; i < TM; ++i)
#pragma unroll
        for (int j = 0; j < TN; ++j) acc[i][j] = 0.f;

    for (int k0 = 0; k0 < K; k0 += BK) {
#pragma unroll
        for (int it = 0; it < (BM * BK / 4) / 256; ++it) {
            int q = t + 256 * it;
            int m = q >> 3;
            int kq = q & 7;
            float4 v = make_float4(0.f, 0.f, 0.f, 0.f);
            if (m < nrow) v = *(const float4*)&A[(size_t)(n0 + m) * K + k0 + 4 * kq];
            if (ELU) {
                v.x = v.x > 0.f ? v.x : expm1f(v.x);
                v.y = v.y > 0.f ? v.y : expm1f(v.y);
                v.z = v.z > 0.f ? v.z : expm1f(v.z);
                v.w = v.w > 0.f ? v.w : expm1f(v.w);
            }
            As[4 * kq + 0][m] = v.x;
            As[4 * kq + 1][m] = v.y;
            As[4 * kq + 2][m] = v.z;
            As[4 * kq + 3][m] = v.w;
        }
#pragma unroll
        for (int it = 0; it < (BK * OUT / 4) / 256; ++it) {
            int q = t + 256 * it;
            int kk = q / (OUT / 4);
            int j = q % (OUT / 4);
            *(float4*)&Bs[kk][4 * j] = *(const float4*)&WT[(size_t)(k0 + kk) * OUT + 4 * j];
        }
        __syncthreads();

        for (int k = 0; k < BK; ++k) {
            float a[TM], b[TN];
            *(float4*)&a[0] = *(const float4*)&As[k][TM * tr];
            *(float4*)&a[4] = *(const float4*)&As[k][TM * tr + 4];
#pragma unroll
            for (int j4 = 0; j4 < TN / 4; ++j4)
                *(float4*)&b[4 * j4] = *(const float4*)&Bs[k][TN * tc + 4 * j4];
#pragma unroll
            for (int i = 0; i < TM; ++i)
#pragma unroll
                for (int j = 0; j < TN; ++j) acc[i][j] = fmaf(a[i], b[j], acc[i][j]);
        }
        __syncthreads();
    }

#pragma unroll
    for (int i = 0; i < TM; ++i) {
        int m = TM * tr + i;
        if (m < nrow) {
#pragma unroll
            for (int j4 = 0; j4 < TN / 4; ++j4)
                *(float4*)&H[(size_t)(n0 + m) * OUT + TN * tc + 4 * j4] =
                    *(const float4*)&acc[i][4 * j4];
        }
    }
#pragma unroll
    for (int i = 0; i < TM; ++i) {
        float vs = 0.f, vd = 0.f;
#pragma unroll
        for (int j = 0; j < TN; ++j) {
            vs = fmaf(acc[i][j], asrc[TN * tc + j], vs);
            vd = fmaf(acc[i][j], adst[TN * tc + j], vd);
        }
#pragma unroll
        for (int off = 8; off >= 1; off >>= 1) {
            vs += __shfl_down(vs, off, 16);
            vd += __shfl_down(vd, off, 16);
        }
        int m = TM * tr + i;
        if (tc == 0 && m < nrow) {
            s_out[n0 + m] = vs;
            d_out_[n0 + m] = vd;
        }
    }
}

// ---- CSR build: histogram -> scan -> scatter ----
__global__ void hist_kernel(const int* __restrict__ row, int* __restrict__ cnt, int E) {
    int i = blockIdx.x * blockDim.x + threadIdx.x;
    if (i < E) atomicAdd(&cnt[row[i]], 1);
}

// per-block exclusive scan (1024 elems/block) + block sums
__global__ __launch_bounds__(1024) void scan1_kernel(const int* __restrict__ cnt,
                                                     int* __restrict__ exc,
                                                     int* __restrict__ bsum, int N) {
    __shared__ int s[1024];
    const int t = threadIdx.x;
    const int i = blockIdx.x * 1024 + t;
    int v = (i < N) ? cnt[i] : 0;
    s[t] = v;
    __syncthreads();
    for (int off = 1; off < 1024; off <<= 1) {
        int x = (t >= off) ? s[t - off] : 0;
        __syncthreads();
        s[t] += x;
        __syncthreads();
    }
    if (i < N) exc[i] = s[t] - v;  // exclusive within block
    if (t == 1023) bsum[blockIdx.x] = s[t];
}

__global__ void scan2_kernel(int* __restrict__ bsum, int* __restrict__ boff, int nb) {
    if (threadIdx.x == 0 && blockIdx.x == 0) {
        int acc = 0;
        for (int i = 0; i < nb; ++i) { boff[i] = acc; acc += bsum[i]; }
    }
}

__global__ void scan3_kernel(int* __restrict__ rp, const int* __restrict__ boff,
                             int N, int E) {
    int i = blockIdx.x * blockDim.x + threadIdx.x;
    if (i < N) rp[i] += boff[i >> 10];
    if (i == 0) rp[N] = E;
}

__global__ void scatter_kernel(const int* __restrict__ row, const int* __restrict__ col,
                               const int* __restrict__ rp, int* __restrict__ off,
                               int* __restrict__ cs, int E) {
    int i = blockIdx.x * blockDim.x + threadIdx.x;
    if (i >= E) return;
    int r = row[i];
    int p = rp[r] + atomicAdd(&off[r], 1);
    cs[p] = col[i];
}

// ---- Fused GAT layer over CSR: one wave per destination row ----
// softmax (max + denom via wave shuffles), then serial edge loop with
// coalesced feature gather; single vector store per row. No atomics.
template <int D>
__global__ __launch_bounds__(256) void gat_csr(
        const int* __restrict__ rp, const int* __restrict__ cs,
        const float* __restrict__ s, const float* __restrict__ d,
        const float* __restrict__ feats, float* __restrict__ out, int N) {
    const int wid = threadIdx.x >> 6;
    const int lane = threadIdx.x & 63;
    const int r = blockIdx.x * 4 + wid;
    if (r >= N) return;
    const int start = rp[r], end = rp[r + 1];
    const float sr = s[r];

    // phase 1: wave-parallel max over edges
    float m = -INFINITY;
    for (int j = start + lane; j < end; j += 64) {
        float e = sr + d[cs[j]];
        e = (e >= 0.f) ? e : NEG_SLOPE * e;
        m = fmaxf(m, e);
    }
#pragma unroll
    for (int off = 32; off >= 1; off >>= 1) m = fmaxf(m, __shfl_xor(m, off));

    // phase 2: wave-parallel denom
    float den = 0.f;
    for (int j = start + lane; j < end; j += 64) {
        float e = sr + d[cs[j]];
        e = (e >= 0.f) ? e : NEG_SLOPE * e;
        den += __expf(e - m);
    }
#pragma unroll
    for (int off = 32; off >= 1; off >>= 1) den += __shfl_xor(den, off);
    const float inv = (end > start) ? 1.f / den : 0.f;

    // phase 3: serial edge loop, lanes parallel over D dims
    constexpr int VPL = D / 64;
    float acc0 = 0.f, acc1 = 0.f;
    for (int j = start; j < end; ++j) {
        int c = __builtin_amdgcn_readfirstlane(cs[j]);  // wave-uniform
        float e = sr + d[c];
        e = (e >= 0.f) ? e : NEG_SLOPE * e;
        float alpha = __expf(e - m) * inv;
        const float* fr = feats + (size_t)c * D;
        if (VPL == 2) {
            float2 v = *(const float2*)&fr[lane * 2];
            acc0 = fmaf(alpha, v.x, acc0);
            acc1 = fmaf(alpha, v.y, acc1);
        } else {
            acc0 = fmaf(alpha, fr[lane], acc0);
        }
    }
    if (VPL == 2)
        *(float2*)&out[(size_t)r * D + lane * 2] = make_float2(acc0, acc1);
    else
        out[(size_t)r * D + lane] = acc0;
}

extern "C" void kernel_launch(void* const* d_in, const int* in_sizes, int n_in,
                              void* d_out, int out_size, void* d_ws, size_t ws_size,
                              hipStream_t stream) {
    const float* x   = (const float*)d_in[0];
    const int*   edg = (const int*)d_in[1];
    const float* W1  = (const float*)d_in[2];
    const float* W2  = (const float*)d_in[3];
    const float* as1 = (const float*)d_in[4];
    const float* ad1 = (const float*)d_in[5];
    const float* as2 = (const float*)d_in[6];
    const float* ad2 = (const float*)d_in[7];

    const int N = in_sizes[0] / 256;
    const int E = in_sizes[1] / 2;
    const int* row = edg;
    const int* col = edg + E;

    // Workspace layout
    char* p = (char*)d_ws;
    float* h1 = (float*)p;  p += (size_t)N * 128 * 4;   // layer1 features (reused as h2)
    float* g1 = (float*)p;  p += (size_t)N * 128 * 4;   // GAT1 output (pre-ELU)
    float* sm = (float*)p;  p += (size_t)N * 4 * 4;     // s1,d1,s2,d2
    float* s1 = sm + (size_t)N * 0;
    float* d1 = sm + (size_t)N * 1;
    float* s2 = sm + (size_t)N * 2;
    float* d2 = sm + (size_t)N * 3;
    float* W1T = (float*)p; p += (size_t)256 * 128 * 4;
    float* W2T = (float*)p; p += (size_t)128 * 64 * 4;
    int* cnt = (int*)p;     p += (size_t)N * 4;         // histogram (zeroed)
    int* off = (int*)p;     p += (size_t)N * 4;         // scatter cursors (zeroed)
    int* rp  = (int*)p;     p += (size_t)(N + 1) * 4;   // CSR row_ptr
    int* bsum = (int*)p;    p += 1024 * 4;
    int* boff = (int*)p;    p += 1024 * 4;
    int* cs  = (int*)p;     p += (size_t)E * 4;         // CSR col indices
    float* h2 = h1;  // h1 dead after gat_csr<128>

    // Zero only the histogram + cursors (adjacent)
    hipMemsetAsync(cnt, 0, (size_t)N * 2 * 4, stream);

    // One-time weight transposes
    transpose_kernel<<<(128 * 256 + 255) / 256, 256, 0, stream>>>(W1, W1T, 128, 256);
    transpose_kernel<<<(64 * 128 + 255) / 256, 256, 0, stream>>>(W2, W2T, 64, 128);

    const int EB = (E + 255) / 256;
    const int GB = (N + 127) / 128;
    const int SB = (N + 1023) / 1024;  // scan blocks

    // CSR build (row shared by both layers)
    hist_kernel<<<EB, 256, 0, stream>>>(row, cnt, E);
    scan1_kernel<<<SB, 1024, 0, stream>>>(cnt, rp, bsum, N);
    scan2_kernel<<<1, 64, 0, stream>>>(bsum, boff, SB);
    scan3_kernel<<<(N + 256) / 256, 256, 0, stream>>>(rp, boff, N, E);
    scatter_kernel<<<EB, 256, 0, stream>>>(row, col, rp, off, cs, E);

    // Layer 1
    gemm_fused<256, 128, 8, false><<<GB, 256, 0, stream>>>(x, W1T, as1, ad1, h1, s1, d1, N);
    gat_csr<128><<<(N + 3) / 4, 256, 0, stream>>>(rp, cs, s1, d1, h1, g1, N);

    // Layer 2 (ELU fused into GEMM2 A-staging)
    gemm_fused<128, 64, 4, true><<<GB, 256, 0, stream>>>(g1, W2T, as2, ad2, h2, s2, d2, N);
    gat_csr<64><<<(N + 3) / 4, 256, 0, stream>>>(rp, cs, s2, d2, h2, (float*)d_out, N);
}